// Round 1
// baseline (249.869 us; speedup 1.0000x reference)
//
#include <hip/hip_runtime.h>
#include <math.h>

// Problem constants
#define NPIX   131072      // 32 * 64 * 64 pixels
#define KCODES 512
#define DDIM   64
#define HWSZ   4096        // 64*64
#define NELEM  8388608     // NPIX * DDIM

// d_out layout (fp32): [0]=loss, [1..1+NELEM)=q_nchw, [1+NELEM]=perplexity,
// [2+NELEM .. 2+2*NELEM)=q_nhwc flat
#define OUT_NCHW_OFF 1
#define OUT_PERP_IDX (1 + NELEM)
#define OUT_NHWC_OFF (2 + NELEM)

// ws layout (fp32 words): [0]=loss, [16..528)=|e|^2, [544..1056)=counts(uint),
// [2048..) = e bf16 hi/lo fragments in MFMA B-layout (byte 8192, 128KB)
#define WS_NRM_OFF  16
#define WS_CNT_OFF  544
#define WS_FRAG_F32 2048

typedef __bf16 bf16x8 __attribute__((ext_vector_type(8)));
typedef float  f32x4  __attribute__((ext_vector_type(4)));

// Fused prep (replaces hipMemsetAsync + vq_norms + vq_pack: 3 dispatches -> 1).
// All threads pack e into bf16 hi/lo MFMA B-fragments (16x16x32: B[k][n],
// n=lane&15, k=(lane>>4)*8+j). Thread tid = [ctile(32)][kstep(2)][h(2)][lane(64)]
// writes its lane's 8 bf16 = 16B, fully coalesced; vq_main loads frag at lane*16B.
// Additionally: tid<512 computes |e|^2, tid in [512,1024) zeros counts,
// tid==0 zeros the loss word. All regions disjoint -> no intra-kernel ordering.
__global__ __launch_bounds__(256) void vq_prep(const float* __restrict__ emb,
                                               float* __restrict__ ws) {
    int tid  = blockIdx.x * 256 + threadIdx.x;   // 0..8191
    if (tid == 0) ws[0] = 0.f;
    if (tid < KCODES) {
        const float4* e4 = reinterpret_cast<const float4*>(emb + tid * DDIM);
        float s = 0.f;
#pragma unroll
        for (int i = 0; i < 16; ++i) {
            float4 v = e4[i];
            s = fmaf(v.x, v.x, s); s = fmaf(v.y, v.y, s);
            s = fmaf(v.z, v.z, s); s = fmaf(v.w, v.w, s);
        }
        ws[WS_NRM_OFF + tid] = s;
    } else if (tid < 2 * KCODES) {
        reinterpret_cast<unsigned*>(ws)[WS_CNT_OFF + (tid - KCODES)] = 0u;
    }

    int lane = tid & 63;
    int h    = (tid >> 6) & 1;
    int ks   = (tid >> 7) & 1;
    int ct   = tid >> 8;                         // 0..31
    int code = ct * 16 + (lane & 15);
    int d0   = ks * 32 + ((lane >> 4) & 3) * 8;
    const float* src = emb + code * DDIM + d0;
    unsigned short us[8];
#pragma unroll
    for (int j = 0; j < 8; ++j) {
        float f = src[j];
        __bf16 hb = (__bf16)f;                       // RTN
        if (h == 0) {
            us[j] = __builtin_bit_cast(unsigned short, hb);
        } else {
            __bf16 lb = (__bf16)(f - (float)hb);
            us[j] = __builtin_bit_cast(unsigned short, lb);
        }
    }
    uint4 v;
    v.x = us[0] | ((unsigned)us[1] << 16);
    v.y = us[2] | ((unsigned)us[3] << 16);
    v.z = us[4] | ((unsigned)us[5] << 16);
    v.w = us[6] | ((unsigned)us[7] << 16);
    reinterpret_cast<uint4*>(ws + WS_FRAG_F32)[tid] = v;
}

// Main: per-block 256 pixels, 4 waves x 64 pixels. A-fragments are loaded
// DIRECTLY from global in fragment layout (the old 69.6KB fp32 LDS staging
// tile only performed an intra-wave transpose; per-instruction coalescing is
// identical: 4x64B segments/wave vs 256B/wave, all bytes consumed once).
// LDS drops 76KB -> ~23KB; __launch_bounds__(256,4) pins 4 blocks/CU
// (16 waves/CU vs previous 8). bf16 hi/lo conversion runs on the same fp32
// values -> bit-identical fragments -> bit-identical argmin/quantized output.
__global__ __launch_bounds__(256, 4) void vq_main(const float* __restrict__ in,
                                                  const float* __restrict__ emb,
                                                  float* __restrict__ out,
                                                  float* __restrict__ ws) {
    __shared__ __align__(16) float q_lds[64 * 65];   // epilogue transpose tile
    __shared__ float    x2_lds[256];
    __shared__ float    nrm_lds[KCODES];
    __shared__ int      idx_lds[256];
    __shared__ unsigned cnt_lds[KCODES];
    __shared__ float    red_tot;

    const int t = threadIdx.x;
    cnt_lds[t] = 0u; cnt_lds[t + 256] = 0u;
    if (t == 0) red_tot = 0.f;

    const int pix0 = blockIdx.x << 8;
    const int b    = pix0 >> 12;
    const int hwb  = pix0 & (HWSZ - 1);

    nrm_lds[t]       = ws[WS_NRM_OFF + t];
    nrm_lds[t + 256] = ws[WS_NRM_OFF + t + 256];

    const int l = t & 63, wid = t >> 6;   // wave handles pixels [wid*64, +64)

    // A-fragments (A[m][k]: m=lane&15, k=(lane>>4)*8+j), hi/lo bf16 split,
    // loaded straight from global NCHW. |x|^2 via intra-wave xor-16/32 reduce.
    const float* base = in + b * (DDIM * HWSZ) + hwb + wid * 64;
    bf16x8 a_hi[4][2], a_lo[4][2];
    float x2p[4];
#pragma unroll
    for (int pt = 0; pt < 4; ++pt) {
        const int hw = pt * 16 + (l & 15);
        float s = 0.f;
#pragma unroll
        for (int ks = 0; ks < 2; ++ks) {
            const int d0 = ks * 32 + ((l >> 4) & 3) * 8;
            const float* p = base + hw + d0 * HWSZ;
            bf16x8 h8, l8;
#pragma unroll
            for (int j = 0; j < 8; ++j) {
                float f = p[j * HWSZ];
                s = fmaf(f, f, s);
                __bf16 hb = (__bf16)f;
                h8[j] = hb;
                l8[j] = (__bf16)(f - (float)hb);
            }
            a_hi[pt][ks] = h8; a_lo[pt][ks] = l8;
        }
        // lanes l, l^16, l^32, l^48 together cover all 64 channels of pixel hw
        s += __shfl_xor(s, 16, 64);
        s += __shfl_xor(s, 32, 64);
        x2p[pt] = s;
    }
    if (l < 16) {
#pragma unroll
        for (int pt = 0; pt < 4; ++pt) x2_lds[wid * 64 + pt * 16 + l] = x2p[pt];
    }
    __syncthreads();

    const uint4* fragp = reinterpret_cast<const uint4*>(ws + WS_FRAG_F32);
    float best[4][4]; int bidx[4][4];
#pragma unroll
    for (int pt = 0; pt < 4; ++pt)
#pragma unroll
    for (int r = 0; r < 4; ++r) { best[pt][r] = 3.4e38f; bidx[pt][r] = 0; }

    // B-frag double buffer: 8 frags/chunk = [ct][ks][h]
    uint4 bcur[8], bnxt[8];
#pragma unroll
    for (int i = 0; i < 8; ++i) {
        int ct = i >> 2, ks = (i >> 1) & 1, h = i & 1;
        bcur[i] = fragp[(((ct) * 2 + ks) * 2 + h) * 64 + l];
    }

    for (int cb = 0; cb < KCODES; cb += 32) {
        int ctb = cb >> 4;
        if (cb + 32 < KCODES) {
#pragma unroll
            for (int i = 0; i < 8; ++i) {
                int ct = i >> 2, ks = (i >> 1) & 1, h = i & 1;
                bnxt[i] = fragp[(((ctb + 2 + ct) * 2 + ks) * 2 + h) * 64 + l];
            }
        }
        // 64 pix x 32 codes: 8 C-tiles, 4-term bf16 split accumulated in fp32
        f32x4 acc[4][2];
#pragma unroll
        for (int pt = 0; pt < 4; ++pt)
#pragma unroll
        for (int ct = 0; ct < 2; ++ct) {
            f32x4 a = {0.f, 0.f, 0.f, 0.f};
#pragma unroll
            for (int ks = 0; ks < 2; ++ks) {
                bf16x8 bh = __builtin_bit_cast(bf16x8, bcur[ct * 4 + ks * 2 + 0]);
                bf16x8 bl = __builtin_bit_cast(bf16x8, bcur[ct * 4 + ks * 2 + 1]);
                a = __builtin_amdgcn_mfma_f32_16x16x32_bf16(a_hi[pt][ks], bh, a, 0, 0, 0);
                a = __builtin_amdgcn_mfma_f32_16x16x32_bf16(a_hi[pt][ks], bl, a, 0, 0, 0);
                a = __builtin_amdgcn_mfma_f32_16x16x32_bf16(a_lo[pt][ks], bh, a, 0, 0, 0);
                a = __builtin_amdgcn_mfma_f32_16x16x32_bf16(a_lo[pt][ks], bl, a, 0, 0, 0);
            }
            acc[pt][ct] = a;
        }
        // argmin update; C/D: col(code)=lane&15, row(pix)=(lane>>4)*4+reg
#pragma unroll
        for (int ct = 0; ct < 2; ++ct) {
            int code = cb + ct * 16 + (l & 15);
            float nv = nrm_lds[code];
#pragma unroll
            for (int pt = 0; pt < 4; ++pt)
#pragma unroll
            for (int r = 0; r < 4; ++r) {
                float d = fmaf(-2.f, acc[pt][ct][r], nv);
                if (d < best[pt][r]) { best[pt][r] = d; bidx[pt][r] = code; }
            }
        }
#pragma unroll
        for (int i = 0; i < 8; ++i) bcur[i] = bnxt[i];
    }

    // Cross-lane argmin within each 16-lane group (codes spread over lane&15);
    // (dist, then idx) min = exact first-min semantics.
#pragma unroll
    for (int off = 1; off < 16; off <<= 1) {
#pragma unroll
        for (int pt = 0; pt < 4; ++pt)
#pragma unroll
        for (int r = 0; r < 4; ++r) {
            float ob = __shfl_xor(best[pt][r], off, 64);
            int   oi = __shfl_xor(bidx[pt][r], off, 64);
            bool take = (ob < best[pt][r]) || (ob == best[pt][r] && oi < bidx[pt][r]);
            if (take) { best[pt][r] = ob; bidx[pt][r] = oi; }
        }
    }
    if ((l & 15) == 0) {
        int q = l >> 4;
        float lp = 0.f;
#pragma unroll
        for (int pt = 0; pt < 4; ++pt)
#pragma unroll
        for (int r = 0; r < 4; ++r) {
            int pixl = wid * 64 + pt * 16 + q * 4 + r;
            idx_lds[pixl] = bidx[pt][r];
            atomicAdd(&cnt_lds[bidx[pt][r]], 1u);
            lp += x2_lds[pixl] + best[pt][r];   // |x-e|^2 = x^2 + (|e|^2 - 2x.e)
        }
        atomicAdd(&red_tot, lp);
    }
    __syncthreads();

    if (t == 0) atomicAdd(ws, red_tot);
    unsigned* gcnt = reinterpret_cast<unsigned*>(ws) + WS_CNT_OFF;
    atomicAdd(gcnt + t, cnt_lds[t]);
    atomicAdd(gcnt + t + 256, cnt_lds[t + 256]);

    // Epilogue: padded LDS tile makes both NHWC and NCHW writes coalesced and
    // LDS-conflict-free (stride 65 mod 32 = 1).
    float* out2 = out + OUT_NCHW_OFF;   // NCHW
    float* out3 = out + OUT_NHWC_OFF;   // NHWC flat (float2-aligned)
    const float2* emb2 = reinterpret_cast<const float2*>(emb);
    float2* out3_2 = reinterpret_cast<float2*>(out3);

    for (int s = 0; s < 4; ++s) {
#pragma unroll
        for (int it = 0; it < 8; ++it) {
            int fid = it * 256 + t;
            int pp  = fid >> 5;
            int c2  = fid & 31;
            int row = idx_lds[s * 64 + pp];
            float2 v = emb2[row * 32 + c2];
            out3_2[(size_t)(pix0 + s * 64 + pp) * 32 + c2] = v;
            q_lds[pp * 65 + c2 * 2 + 0] = v.x;
            q_lds[pp * 65 + c2 * 2 + 1] = v.y;
        }
        __syncthreads();
#pragma unroll
        for (int it = 0; it < 16; ++it) {
            int did = it * 256 + t;
            int c   = did >> 6;
            int hwl = did & 63;
            out2[(size_t)(b * DDIM + c) * HWSZ + hwb + s * 64 + hwl] = q_lds[hwl * 65 + c];
        }
        __syncthreads();
    }
}

__global__ __launch_bounds__(256) void vq_fin(float* __restrict__ out,
                                              const float* __restrict__ ws) {
    const unsigned* cnt = reinterpret_cast<const unsigned*>(ws) + WS_CNT_OFF;
    int t = threadIdx.x;  // 256
    double s = 0.0;
#pragma unroll
    for (int k = t; k < KCODES; k += 256) {
        double p = (double)cnt[k] / (double)NPIX;
        s += p * log(p + 1e-10);
    }
#pragma unroll
    for (int o = 32; o > 0; o >>= 1) s += __shfl_xor(s, o, 64);
    __shared__ double rd[4];
    if ((t & 63) == 0) rd[t >> 6] = s;
    __syncthreads();
    if (t == 0) {
        double tot = rd[0] + rd[1] + rd[2] + rd[3];
        out[OUT_PERP_IDX] = (float)exp(-tot);
        out[0] = 0.25f * ws[0] / (float)NELEM;
    }
}

extern "C" void kernel_launch(void* const* d_in, const int* in_sizes, int n_in,
                              void* d_out, int out_size, void* d_ws, size_t ws_size,
                              hipStream_t stream) {
    const float* in  = (const float*)d_in[0];
    const float* emb = (const float*)d_in[1];
    float* out = (float*)d_out;
    float* ws  = (float*)d_ws;

    // vq_prep zeroes loss+counts itself and overwrites norms + frag region:
    // no memset needed (ws must not be assumed preserved across runs — it isn't).
    vq_prep<<<32, 256, 0, stream>>>(emb, ws);
    vq_main<<<NPIX / 256, 256, 0, stream>>>(in, emb, out, ws);
    vq_fin<<<1, 256, 0, stream>>>(out, ws);
}

// Round 2
// 141.775 us; speedup vs baseline: 1.7624x; 1.7624x over previous
//
#include <hip/hip_runtime.h>
#include <math.h>

// Problem constants
#define NPIX   131072      // 32 * 64 * 64 pixels
#define KCODES 512
#define DDIM   64
#define HWSZ   4096        // 64*64
#define NELEM  8388608     // NPIX * DDIM

// d_out layout (fp32): [0]=loss, [1..1+NELEM)=q_nchw, [1+NELEM]=perplexity,
// [2+NELEM .. 2+2*NELEM)=q_nhwc flat
#define OUT_NCHW_OFF 1
#define OUT_PERP_IDX (1 + NELEM)
#define OUT_NHWC_OFF (2 + NELEM)

// ws layout (fp32 words): [0]=loss, [16..528)=|e|^2, [544..1056)=counts(uint),
// [2048..) = e bf16 hi/lo fragments in MFMA B-layout (byte 8192, 128KB)
#define WS_NRM_OFF  16
#define WS_CNT_OFF  544
#define WS_FRAG_F32 2048

typedef __bf16 bf16x8 __attribute__((ext_vector_type(8)));
typedef float  f32x4  __attribute__((ext_vector_type(4)));

// Fused prep (memset + norms + pack in one dispatch). Thread tid =
// [ctile(32)][kstep(2)][h(2)][lane(64)] packs e into bf16 hi/lo MFMA
// B-fragments (16x16x32: B[k][n], n=lane&15, k=(lane>>4)*8+j); 16B coalesced.
// tid<512 computes |e|^2; tid in [512,1024) zeros counts; tid 0 zeros loss.
__global__ __launch_bounds__(256) void vq_prep(const float* __restrict__ emb,
                                               float* __restrict__ ws) {
    int tid  = blockIdx.x * 256 + threadIdx.x;   // 0..8191
    if (tid == 0) ws[0] = 0.f;
    if (tid < KCODES) {
        const float4* e4 = reinterpret_cast<const float4*>(emb + tid * DDIM);
        float s = 0.f;
#pragma unroll
        for (int i = 0; i < 16; ++i) {
            float4 v = e4[i];
            s = fmaf(v.x, v.x, s); s = fmaf(v.y, v.y, s);
            s = fmaf(v.z, v.z, s); s = fmaf(v.w, v.w, s);
        }
        ws[WS_NRM_OFF + tid] = s;
    } else if (tid < 2 * KCODES) {
        reinterpret_cast<unsigned*>(ws)[WS_CNT_OFF + (tid - KCODES)] = 0u;
    }

    int lane = tid & 63;
    int h    = (tid >> 6) & 1;
    int ks   = (tid >> 7) & 1;
    int ct   = tid >> 8;                         // 0..31
    int code = ct * 16 + (lane & 15);
    int d0   = ks * 32 + ((lane >> 4) & 3) * 8;
    const float* src = emb + code * DDIM + d0;
    unsigned short us[8];
#pragma unroll
    for (int j = 0; j < 8; ++j) {
        float f = src[j];
        __bf16 hb = (__bf16)f;                       // RTN
        if (h == 0) {
            us[j] = __builtin_bit_cast(unsigned short, hb);
        } else {
            __bf16 lb = (__bf16)(f - (float)hb);
            us[j] = __builtin_bit_cast(unsigned short, lb);
        }
    }
    uint4 v;
    v.x = us[0] | ((unsigned)us[1] << 16);
    v.y = us[2] | ((unsigned)us[3] << 16);
    v.z = us[4] | ((unsigned)us[5] << 16);
    v.w = us[6] | ((unsigned)us[7] << 16);
    reinterpret_cast<uint4*>(ws + WS_FRAG_F32)[tid] = v;
}

// Main. Per-block 256 pixels, 4 waves x 64 pixels. R1 lesson: direct-from-
// global A-fragments are right, but the full live set (A 64 + B dbuf 64 +
// acc 32 + best 32 regs) spilled under the 128-VGPR cap of (256,4) ->
// 530MB scratch traffic. Fix: TWO SEQUENTIAL PASSES of 2 pixel-tiles each,
// argmin finalized per pass. Per-pass live set: A 32 + bcur 32 (single-
// buffered) + acc 16 + best/bidx 16 + misc ~20 = ~115 regs < 128.
// Cost: B-fragments read twice per wave (extra ~256MB L2 traffic, absorbed
// by 34.5 TB/s L2) — paid for by 2x occupancy (4 blocks/CU vs 2).
// bf16 hi/lo conversion on identical fp32 values -> bit-identical argmin.
__global__ __launch_bounds__(256, 4) void vq_main(const float* __restrict__ in,
                                                  const float* __restrict__ emb,
                                                  float* __restrict__ out,
                                                  float* __restrict__ ws) {
    __shared__ __align__(16) float q_lds[64 * 65];   // epilogue transpose tile
    __shared__ float    x2_lds[256];
    __shared__ float    nrm_lds[KCODES];
    __shared__ int      idx_lds[256];
    __shared__ unsigned cnt_lds[KCODES];
    __shared__ float    red_tot;

    const int t = threadIdx.x;
    cnt_lds[t] = 0u; cnt_lds[t + 256] = 0u;
    if (t == 0) red_tot = 0.f;

    const int pix0 = blockIdx.x << 8;
    const int b    = pix0 >> 12;
    const int hwb  = pix0 & (HWSZ - 1);

    nrm_lds[t]       = ws[WS_NRM_OFF + t];
    nrm_lds[t + 256] = ws[WS_NRM_OFF + t + 256];
    __syncthreads();   // nrm_lds + cnt_lds + red_tot ready for all waves

    const int l = t & 63, wid = t >> 6;   // wave handles pixels [wid*64, +64)
    const float* base = in + b * (DDIM * HWSZ) + hwb + wid * 64;
    const uint4* fragp = reinterpret_cast<const uint4*>(ws + WS_FRAG_F32);

#pragma unroll 1
    for (int p = 0; p < 2; ++p) {
        // A-fragments (A[m][k]: m=lane&15, k=(lane>>4)*8+j), hi/lo bf16 split,
        // loaded straight from global NCHW. |x|^2 via xor-16/32 reduce
        // (lanes l, l^16, l^32, l^48 cover all 64 channels of pixel hw).
        bf16x8 a_hi[2][2], a_lo[2][2];
        float x2p[2];
#pragma unroll
        for (int pt = 0; pt < 2; ++pt) {
            const int hw = p * 32 + pt * 16 + (l & 15);
            float s = 0.f;
#pragma unroll
            for (int ks = 0; ks < 2; ++ks) {
                const int d0 = ks * 32 + ((l >> 4) & 3) * 8;
                const float* pp = base + hw + d0 * HWSZ;
                bf16x8 h8, l8;
#pragma unroll
                for (int j = 0; j < 8; ++j) {
                    float f = pp[j * HWSZ];
                    s = fmaf(f, f, s);
                    __bf16 hb = (__bf16)f;
                    h8[j] = hb;
                    l8[j] = (__bf16)(f - (float)hb);
                }
                a_hi[pt][ks] = h8; a_lo[pt][ks] = l8;
            }
            s += __shfl_xor(s, 16, 64);
            s += __shfl_xor(s, 32, 64);
            x2p[pt] = s;
        }
        if (l < 16) {
            x2_lds[wid * 64 + p * 32 + l]      = x2p[0];
            x2_lds[wid * 64 + p * 32 + 16 + l] = x2p[1];
        }

        float best[2][4]; int bidx[2][4];
#pragma unroll
        for (int pt = 0; pt < 2; ++pt)
#pragma unroll
        for (int r = 0; r < 4; ++r) { best[pt][r] = 3.4e38f; bidx[pt][r] = 0; }

        for (int cb = 0; cb < KCODES; cb += 32) {
            const int ctb = cb >> 4;
            // B-frags single-buffered: 8 frags/chunk = [ct][ks][h] (L2-resident)
            uint4 bcur[8];
#pragma unroll
            for (int i = 0; i < 8; ++i) {
                int ct = i >> 2, ks = (i >> 1) & 1, h = i & 1;
                bcur[i] = fragp[(((ctb + ct) * 2 + ks) * 2 + h) * 64 + l];
            }
            // 32 pix x 32 codes: 4 C-tiles, 4-term bf16 split in fp32
            f32x4 acc[2][2];
#pragma unroll
            for (int pt = 0; pt < 2; ++pt)
#pragma unroll
            for (int ct = 0; ct < 2; ++ct) {
                f32x4 a = {0.f, 0.f, 0.f, 0.f};
#pragma unroll
                for (int ks = 0; ks < 2; ++ks) {
                    bf16x8 bh = __builtin_bit_cast(bf16x8, bcur[ct * 4 + ks * 2 + 0]);
                    bf16x8 bl = __builtin_bit_cast(bf16x8, bcur[ct * 4 + ks * 2 + 1]);
                    a = __builtin_amdgcn_mfma_f32_16x16x32_bf16(a_hi[pt][ks], bh, a, 0, 0, 0);
                    a = __builtin_amdgcn_mfma_f32_16x16x32_bf16(a_hi[pt][ks], bl, a, 0, 0, 0);
                    a = __builtin_amdgcn_mfma_f32_16x16x32_bf16(a_lo[pt][ks], bh, a, 0, 0, 0);
                    a = __builtin_amdgcn_mfma_f32_16x16x32_bf16(a_lo[pt][ks], bl, a, 0, 0, 0);
                }
                acc[pt][ct] = a;
            }
            // argmin update; C/D: col(code)=lane&15, row(pix)=(lane>>4)*4+reg
#pragma unroll
            for (int ct = 0; ct < 2; ++ct) {
                int code = cb + ct * 16 + (l & 15);
                float nv = nrm_lds[code];
#pragma unroll
                for (int pt = 0; pt < 2; ++pt)
#pragma unroll
                for (int r = 0; r < 4; ++r) {
                    float d = fmaf(-2.f, acc[pt][ct][r], nv);
                    if (d < best[pt][r]) { best[pt][r] = d; bidx[pt][r] = code; }
                }
            }
        }

        // Cross-lane argmin within each 16-lane group (codes spread over
        // lane&15); (dist, then idx) min = exact first-min semantics.
#pragma unroll
        for (int off = 1; off < 16; off <<= 1) {
#pragma unroll
            for (int pt = 0; pt < 2; ++pt)
#pragma unroll
            for (int r = 0; r < 4; ++r) {
                float ob = __shfl_xor(best[pt][r], off, 64);
                int   oi = __shfl_xor(bidx[pt][r], off, 64);
                bool take = (ob < best[pt][r]) || (ob == best[pt][r] && oi < bidx[pt][r]);
                if (take) { best[pt][r] = ob; bidx[pt][r] = oi; }
            }
        }
        if ((l & 15) == 0) {
            int q = l >> 4;
            float lp = 0.f;
#pragma unroll
            for (int pt = 0; pt < 2; ++pt)
#pragma unroll
            for (int r = 0; r < 4; ++r) {
                int pixl = wid * 64 + p * 32 + pt * 16 + q * 4 + r;
                idx_lds[pixl] = bidx[pt][r];
                atomicAdd(&cnt_lds[bidx[pt][r]], 1u);
                lp += x2_lds[pixl] + best[pt][r];   // |x-e|^2 = x^2 + (|e|^2 - 2x.e)
            }
            atomicAdd(&red_tot, lp);
        }
    }
    __syncthreads();

    if (t == 0) atomicAdd(ws, red_tot);
    unsigned* gcnt = reinterpret_cast<unsigned*>(ws) + WS_CNT_OFF;
    atomicAdd(gcnt + t, cnt_lds[t]);
    atomicAdd(gcnt + t + 256, cnt_lds[t + 256]);

    // Epilogue: padded LDS tile makes both NHWC and NCHW writes coalesced and
    // LDS-conflict-free (stride 65 mod 32 = 1).
    float* out2 = out + OUT_NCHW_OFF;   // NCHW
    float* out3 = out + OUT_NHWC_OFF;   // NHWC flat (float2-aligned)
    const float2* emb2 = reinterpret_cast<const float2*>(emb);
    float2* out3_2 = reinterpret_cast<float2*>(out3);

    for (int s = 0; s < 4; ++s) {
#pragma unroll
        for (int it = 0; it < 8; ++it) {
            int fid = it * 256 + t;
            int pp  = fid >> 5;
            int c2  = fid & 31;
            int row = idx_lds[s * 64 + pp];
            float2 v = emb2[row * 32 + c2];
            out3_2[(size_t)(pix0 + s * 64 + pp) * 32 + c2] = v;
            q_lds[pp * 65 + c2 * 2 + 0] = v.x;
            q_lds[pp * 65 + c2 * 2 + 1] = v.y;
        }
        __syncthreads();
#pragma unroll
        for (int it = 0; it < 16; ++it) {
            int did = it * 256 + t;
            int c   = did >> 6;
            int hwl = did & 63;
            out2[(size_t)(b * DDIM + c) * HWSZ + hwb + s * 64 + hwl] = q_lds[hwl * 65 + c];
        }
        __syncthreads();
    }
}

__global__ __launch_bounds__(256) void vq_fin(float* __restrict__ out,
                                              const float* __restrict__ ws) {
    const unsigned* cnt = reinterpret_cast<const unsigned*>(ws) + WS_CNT_OFF;
    int t = threadIdx.x;  // 256
    double s = 0.0;
#pragma unroll
    for (int k = t; k < KCODES; k += 256) {
        double p = (double)cnt[k] / (double)NPIX;
        s += p * log(p + 1e-10);
    }
#pragma unroll
    for (int o = 32; o > 0; o >>= 1) s += __shfl_xor(s, o, 64);
    __shared__ double rd[4];
    if ((t & 63) == 0) rd[t >> 6] = s;
    __syncthreads();
    if (t == 0) {
        double tot = rd[0] + rd[1] + rd[2] + rd[3];
        out[OUT_PERP_IDX] = (float)exp(-tot);
        out[0] = 0.25f * ws[0] / (float)NELEM;
    }
}

extern "C" void kernel_launch(void* const* d_in, const int* in_sizes, int n_in,
                              void* d_out, int out_size, void* d_ws, size_t ws_size,
                              hipStream_t stream) {
    const float* in  = (const float*)d_in[0];
    const float* emb = (const float*)d_in[1];
    float* out = (float*)d_out;
    float* ws  = (float*)d_ws;

    // vq_prep zeroes loss+counts itself and overwrites norms + frag region.
    vq_prep<<<32, 256, 0, stream>>>(emb, ws);
    vq_main<<<NPIX / 256, 256, 0, stream>>>(in, emb, out, ws);
    vq_fin<<<1, 256, 0, stream>>>(out, ws);
}